// Round 1
// baseline (967.347 us; speedup 1.0000x reference)
//
#include <hip/hip_runtime.h>
#include <hip/hip_bf16.h>

#define T_DIM 512
#define S_DIM 512
#define B_DIM 8
#define E_DIM 1024
#define H_CNT 16
#define D_DIM 64
#define N_HEADS 128
#define M_ROWS 4096
#define K_DIM 1024
#define EPS_C 1e-6f

using f32x4  = __attribute__((ext_vector_type(4))) float;
using short8 = __attribute__((ext_vector_type(8))) short;

static __device__ __forceinline__ ushort f2bf(float x){
  __hip_bfloat16 h = __float2bfloat16(x);
  return *reinterpret_cast<ushort*>(&h);
}
static __device__ __forceinline__ float bf2f(ushort u){
  __hip_bfloat16 h = *reinterpret_cast<__hip_bfloat16*>(&u);
  return __bfloat162float(h);
}

// ---- transpose + cvt weights: Wt[f][e] = bf16(W[e][f]) ----
__global__ __launch_bounds__(256) void wtrans_kernel(const float* __restrict__ W,
                                                     ushort* __restrict__ Wt){
  __shared__ float tile[32][33];
  const int bx = blockIdx.x * 32, by = blockIdx.y * 32;
  const int x = threadIdx.x & 31, y = threadIdx.x >> 5;
  #pragma unroll
  for (int j = 0; j < 32; j += 8)
    tile[y + j][x] = W[(size_t)(by + y + j) * E_DIM + bx + x];
  __syncthreads();
  #pragma unroll
  for (int j = 0; j < 32; j += 8)
    Wt[(size_t)(bx + y + j) * E_DIM + by + x] = f2bf(tile[x][y + j]);
}

// ---- GEMM: C = A(f32,[4096][1024]) x Bm(bf16,[1024][1024], row-major-K "B^T")
// MODE 0: bf16 out scattered to [b*16+h][t][d];  MODE 1: same + *0.125
// MODE 2: f32 out [4096][1024] + bias
template<int MODE>
__global__ __launch_bounds__(256) void gemm_bt(const float* __restrict__ A,
                                               const ushort* __restrict__ Bm,
                                               void* __restrict__ Cout,
                                               const float* __restrict__ bias){
  constexpr int BK = 32;
  __shared__ ushort lA[128 * BK];
  __shared__ ushort lB[128 * BK];
  const int tid = threadIdx.x;
  const int l = tid & 63, w = tid >> 6;
  const int wm = w >> 1, wn = w & 1;
  const int lq = l >> 4, lr = l & 15;
  const int m0 = blockIdx.y * 128, n0 = blockIdx.x * 128;
  const int srow = tid >> 1, shalf = tid & 1;

  f32x4 acc[4][4];
  #pragma unroll
  for (int i = 0; i < 4; i++)
    #pragma unroll
    for (int j = 0; j < 4; j++) acc[i][j] = (f32x4){0.f, 0.f, 0.f, 0.f};

  for (int k0 = 0; k0 < K_DIM; k0 += BK){
    // stage A (f32 -> bf16), rows: srow, half-k: shalf
    {
      const float* ga = A + (size_t)(m0 + srow) * K_DIM + k0 + shalf * 16;
      ushort tmp[16];
      #pragma unroll
      for (int j = 0; j < 16; j += 4){
        float4 vv = *reinterpret_cast<const float4*>(ga + j);
        tmp[j] = f2bf(vv.x); tmp[j+1] = f2bf(vv.y); tmp[j+2] = f2bf(vv.z); tmp[j+3] = f2bf(vv.w);
      }
      #pragma unroll
      for (int j = 0; j < 2; j++){
        int slot = (shalf * 2 + j) ^ (srow & 3);
        *reinterpret_cast<short8*>(reinterpret_cast<char*>(lA) + srow * 64 + slot * 16) =
            *reinterpret_cast<short8*>(&tmp[j * 8]);
      }
      const ushort* gb = Bm + (size_t)(n0 + srow) * K_DIM + k0 + shalf * 16;
      #pragma unroll
      for (int j = 0; j < 2; j++){
        short8 vv = *reinterpret_cast<const short8*>(gb + j * 8);
        int slot = (shalf * 2 + j) ^ (srow & 3);
        *reinterpret_cast<short8*>(reinterpret_cast<char*>(lB) + srow * 64 + slot * 16) = vv;
      }
    }
    __syncthreads();
    short8 fa[4], fb[4];
    #pragma unroll
    for (int i = 0; i < 4; i++){
      int row = wm * 64 + i * 16 + lr;
      fa[i] = *reinterpret_cast<const short8*>(reinterpret_cast<const char*>(lA) + row * 64 + ((lq ^ (row & 3)) << 4));
      int col = wn * 64 + i * 16 + lr;
      fb[i] = *reinterpret_cast<const short8*>(reinterpret_cast<const char*>(lB) + col * 64 + ((lq ^ (col & 3)) << 4));
    }
    #pragma unroll
    for (int i = 0; i < 4; i++)
      #pragma unroll
      for (int j = 0; j < 4; j++)
        acc[i][j] = __builtin_amdgcn_mfma_f32_16x16x32_bf16(fa[i], fb[j], acc[i][j], 0, 0, 0);
    __syncthreads();
  }

  #pragma unroll
  for (int i = 0; i < 4; i++)
    #pragma unroll
    for (int j = 0; j < 4; j++)
      #pragma unroll
      for (int r = 0; r < 4; r++){
        int gm = m0 + wm * 64 + i * 16 + lq * 4 + r;
        int gn = n0 + wn * 64 + j * 16 + lr;
        float v = acc[i][j][r];
        if constexpr (MODE == 2){
          reinterpret_cast<float*>(Cout)[(size_t)gm * E_DIM + gn] = v + bias[gn];
        } else {
          if constexpr (MODE == 1) v *= 0.125f;
          int t = gm >> 3, b = gm & 7, h = gn >> 6, d = gn & 63;
          reinterpret_cast<ushort*>(Cout)[(((size_t)(b * H_CNT + h) * T_DIM + t) << 6) + d] = f2bf(v);
        }
      }
}

// ---- fused monotonic-attention recurrence, one head per block ----
// LDS layout (dynamic): vpT 65536 | p_sm 32768 | a_sm 16384 | red 32768 | scr 256
__global__ __launch_bounds__(512) void rec_kernel(const ushort* __restrict__ qp,
                                                  const ushort* __restrict__ kp,
                                                  const ushort* __restrict__ vp,
                                                  float* __restrict__ attn,
                                                  const float* __restrict__ ebias_p){
  extern __shared__ char smem[];
  float*  p_sm = reinterpret_cast<float*>(smem + 65536);
  float*  red  = reinterpret_cast<float*>(smem + 114688);
  float*  scr0 = reinterpret_cast<float*>(smem + 147456);
  float*  scr1 = reinterpret_cast<float*>(smem + 147488);

  const int tid = threadIdx.x;
  const int l = tid & 63, w = tid >> 6;
  const int kg = l >> 4, lr = l & 15;
  const int n = blockIdx.x;
  const int bb = n >> 4, hh = n & 15;
  const float ebias = ebias_p[0];

  const ushort* kph = kp + (size_t)n * (S_DIM * D_DIM);
  const ushort* vph = vp + (size_t)n * (S_DIM * D_DIM);
  const ushort* qph = qp + (size_t)n * (T_DIM * D_DIM);

  // stage V transposed + swizzled: elem (d,s) at byte ((d<<10)+(s<<1)) ^ ((d&7)<<4)
  for (int c = tid; c < 4096; c += 512){
    int s = c >> 3, d8 = (c & 7) * 8;
    short8 v = *reinterpret_cast<const short8*>(vph + s * 64 + d8);
    #pragma unroll
    for (int j = 0; j < 8; j++){
      int d = d8 + j;
      int byt = ((d << 10) + (s << 1)) ^ ((d & 7) << 4);
      *reinterpret_cast<ushort*>(smem + byt) = (ushort)v[j];
    }
  }
  float aprev = (tid == 0) ? 1.f : 0.f;
  __syncthreads();

  for (int c = 0; c < 32; ++c){
    const int t0 = c * 16;
    // ---- energy: E[16 x 512] via MFMA, sigmoid -> p_sm (f32) ----
    short8 fa[2];
    #pragma unroll
    for (int kk = 0; kk < 2; kk++)
      fa[kk] = *reinterpret_cast<const short8*>(qph + (t0 + lr) * 64 + kk * 32 + kg * 8);
    #pragma unroll
    for (int fc = 0; fc < 4; fc++){
      int s = w * 64 + fc * 16 + lr;
      f32x4 e = (f32x4){0.f, 0.f, 0.f, 0.f};
      #pragma unroll
      for (int kk = 0; kk < 2; kk++){
        short8 fb = *reinterpret_cast<const short8*>(kph + s * 64 + kk * 32 + kg * 8);
        e = __builtin_amdgcn_mfma_f32_16x16x32_bf16(fa[kk], fb, e, 0, 0, 0);
      }
      #pragma unroll
      for (int r = 0; r < 4; r++){
        float ev = e[r] + ebias;
        float pv = 1.f / (1.f + __expf(-ev));
        p_sm[((kg * 4 + r) << 9) + s] = pv;
      }
    }
    __syncthreads();

    // ---- 16 serial recurrence steps (all f32) ----
    for (int tt = 0; tt < 16; ++tt){
      float p = p_sm[(tt << 9) + tid];
      float inc = 1.f - p;
      #pragma unroll
      for (int off = 1; off < 64; off <<= 1){
        float y = __shfl_up(inc, off);
        if (l >= off) inc *= y;
      }
      if (l == 63) scr0[w] = inc;
      __syncthreads();
      float wpref = 1.f;
      #pragma unroll
      for (int j = 0; j < 7; j++) if (j < w) wpref *= scr0[j];
      float excl = __shfl_up(inc, 1);
      if (l == 0) excl = 1.f;
      float cp = excl * wpref;
      float cl = fmaxf(cp, EPS_C);
      float cs = aprev / cl;
      #pragma unroll
      for (int off = 1; off < 64; off <<= 1){
        float y = __shfl_up(cs, off);
        if (l >= off) cs += y;
      }
      if (l == 63) scr1[w] = cs;
      __syncthreads();
      float spref = 0.f;
      #pragma unroll
      for (int j = 0; j < 7; j++) if (j < w) spref += scr1[j];
      float alpha = fminf(p * cp * (cs + spref), 1.f);
      int byt = ((tt << 10) + (tid << 1)) ^ ((tt & 7) << 4);
      *reinterpret_cast<ushort*>(smem + 98304 + byt) = f2bf(alpha);
      aprev = alpha;  // recurrence carries PRE-dump alpha
    }
    __syncthreads();

    // ---- mass-dump fixup: a[t][511] = 1 - clip(sum_{s<511} a[t][s]) ----
    #pragma unroll
    for (int r2 = 0; r2 < 2; r2++){
      int t = w * 2 + r2;
      int sbyt = ((t << 10) + (l << 4)) ^ ((t & 7) << 4);
      short8 av = *reinterpret_cast<const short8*>(smem + 98304 + sbyt);
      float partial = 0.f;
      #pragma unroll
      for (int j = 0; j < 8; j++) partial += bf2f((ushort)av[j]);
      float last = bf2f((ushort)av[7]);
      #pragma unroll
      for (int off = 1; off < 64; off <<= 1) partial += __shfl_xor(partial, off);
      float a511 = __shfl(last, 63);
      float tot = partial - a511;
      if (l == 63){
        float nv = 1.f - fminf(fmaxf(tot, 0.f), 1.f);
        int wb = ((t << 10) + (511 << 1)) ^ ((t & 7) << 4);
        *reinterpret_cast<ushort*>(smem + 98304 + wb) = f2bf(nv);
      }
    }
    __syncthreads();

    // ---- attn: [16 x 64] = alpha[16 x 512] x V, K split across waves ----
    f32x4 ac[4];
    #pragma unroll
    for (int dc = 0; dc < 4; dc++) ac[dc] = (f32x4){0.f, 0.f, 0.f, 0.f};
    #pragma unroll
    for (int kk = 0; kk < 2; kk++){
      int sb = w * 64 + kk * 32 + kg * 8;
      int ab = ((lr << 10) + (sb << 1)) ^ ((lr & 7) << 4);
      short8 faA = *reinterpret_cast<const short8*>(smem + 98304 + ab);
      #pragma unroll
      for (int dc = 0; dc < 4; dc++){
        int d = dc * 16 + lr;
        int vb = ((d << 10) + (sb << 1)) ^ ((d & 7) << 4);
        short8 fbV = *reinterpret_cast<const short8*>(smem + vb);
        ac[dc] = __builtin_amdgcn_mfma_f32_16x16x32_bf16(faA, fbV, ac[dc], 0, 0, 0);
      }
    }
    #pragma unroll
    for (int dc = 0; dc < 4; dc++)
      #pragma unroll
      for (int r = 0; r < 4; r++)
        red[w * 1024 + (kg * 4 + r) * 64 + dc * 16 + lr] = ac[dc][r];
    __syncthreads();
    #pragma unroll
    for (int it = 0; it < 2; ++it){
      int idx = it * 512 + tid;
      float s = 0.f;
      #pragma unroll
      for (int ww = 0; ww < 8; ww++) s += red[ww * 1024 + idx];
      int t = idx >> 6, d = idx & 63;
      attn[((size_t)(t0 + t) * B_DIM + bb) * E_DIM + hh * 64 + d] = s;
    }
    __syncthreads();
  }
}

extern "C" void kernel_launch(void* const* d_in, const int* in_sizes, int n_in,
                              void* d_out, int out_size, void* d_ws, size_t ws_size,
                              hipStream_t stream){
  (void)in_sizes; (void)n_in; (void)out_size; (void)ws_size;
  const float* q  = (const float*)d_in[0];
  const float* k  = (const float*)d_in[1];
  const float* v  = (const float*)d_in[2];
  const float* Wq = (const float*)d_in[3];
  const float* Wk = (const float*)d_in[4];
  const float* Wv = (const float*)d_in[5];
  const float* Wo = (const float*)d_in[6];
  const float* bo = (const float*)d_in[7];
  const float* eb = (const float*)d_in[8];

  char* ws = (char*)d_ws;
  ushort* wqt  = (ushort*)(ws);
  ushort* wkt  = (ushort*)(ws + (1u << 21));
  ushort* wvt  = (ushort*)(ws + 2u * (1u << 21));
  ushort* wot  = (ushort*)(ws + 3u * (1u << 21));
  ushort* qp   = (ushort*)(ws + 4u * (1u << 21));
  ushort* kp   = (ushort*)(ws + 4u * (1u << 21) + (1u << 23));
  ushort* vp   = (ushort*)(ws + 4u * (1u << 21) + 2u * (1u << 23));
  float*  attn = (float*) (ws + 4u * (1u << 21) + 3u * (1u << 23));

  dim3 tb(256);
  dim3 tgT(32, 32);
  wtrans_kernel<<<tgT, tb, 0, stream>>>(Wq, wqt);
  wtrans_kernel<<<tgT, tb, 0, stream>>>(Wk, wkt);
  wtrans_kernel<<<tgT, tb, 0, stream>>>(Wv, wvt);
  wtrans_kernel<<<tgT, tb, 0, stream>>>(Wo, wot);

  dim3 gg(E_DIM / 128, M_ROWS / 128);
  gemm_bt<1><<<gg, tb, 0, stream>>>(q, wqt, (void*)qp, nullptr);
  gemm_bt<0><<<gg, tb, 0, stream>>>(k, wkt, (void*)kp, nullptr);
  gemm_bt<0><<<gg, tb, 0, stream>>>(v, wvt, (void*)vp, nullptr);

  hipFuncSetAttribute((const void*)rec_kernel,
                      hipFuncAttributeMaxDynamicSharedMemorySize, 147712);
  rec_kernel<<<dim3(N_HEADS), dim3(512), 147712, stream>>>(qp, kp, vp, attn, eb);

  gemm_bt<2><<<gg, tb, 0, stream>>>(attn, wot, d_out, bo);
}

// Round 2
// 488.121 us; speedup vs baseline: 1.9818x; 1.9818x over previous
//
#include <hip/hip_runtime.h>
#include <hip/hip_bf16.h>

#define T_DIM 512
#define S_DIM 512
#define B_DIM 8
#define E_DIM 1024
#define H_CNT 16
#define D_DIM 64
#define N_HEADS 128
#define M_ROWS 4096
#define K_DIM 1024
#define EPS_C 1e-6f

using f32x4  = __attribute__((ext_vector_type(4))) float;
using short8 = __attribute__((ext_vector_type(8))) short;

static __device__ __forceinline__ ushort f2bf(float x){
  __hip_bfloat16 h = __float2bfloat16(x);
  return *reinterpret_cast<ushort*>(&h);
}
static __device__ __forceinline__ float rcpf(float x){
  return __builtin_amdgcn_rcpf(x);
}

// DPP move: dest = src[perm] for enabled rows, else oldv. Compile-time ctrl/mask.
template<int CTRL, int RMASK>
static __device__ __forceinline__ float dppf(float x, float oldv){
  return __int_as_float(__builtin_amdgcn_update_dpp(
      __float_as_int(oldv), __float_as_int(x), CTRL, RMASK, 0xf, false));
}
// inclusive 64-lane scans (GCN classic: row_shr 1,2,4,8 + bcast15 + bcast31)
static __device__ __forceinline__ float wscan_mul(float x){
  x *= dppf<0x111,0xf>(x, 1.f);
  x *= dppf<0x112,0xf>(x, 1.f);
  x *= dppf<0x114,0xf>(x, 1.f);
  x *= dppf<0x118,0xf>(x, 1.f);
  x *= dppf<0x142,0xa>(x, 1.f);   // bcast15 -> rows 1,3
  x *= dppf<0x143,0xc>(x, 1.f);   // bcast31 -> rows 2,3
  return x;
}
static __device__ __forceinline__ float wscan_add(float x){
  x += dppf<0x111,0xf>(x, 0.f);
  x += dppf<0x112,0xf>(x, 0.f);
  x += dppf<0x114,0xf>(x, 0.f);
  x += dppf<0x118,0xf>(x, 0.f);
  x += dppf<0x142,0xa>(x, 0.f);
  x += dppf<0x143,0xc>(x, 0.f);
  return x;
}

// ---- transpose + cvt weights: Wt[f][e] = bf16(W[e][f]) ----
__global__ __launch_bounds__(256) void wtrans_kernel(const float* __restrict__ W,
                                                     ushort* __restrict__ Wt){
  __shared__ float tile[32][33];
  const int bx = blockIdx.x * 32, by = blockIdx.y * 32;
  const int x = threadIdx.x & 31, y = threadIdx.x >> 5;
  #pragma unroll
  for (int j = 0; j < 32; j += 8)
    tile[y + j][x] = W[(size_t)(by + y + j) * E_DIM + bx + x];
  __syncthreads();
  #pragma unroll
  for (int j = 0; j < 32; j += 8)
    Wt[(size_t)(bx + y + j) * E_DIM + by + x] = f2bf(tile[x][y + j]);
}

// ---- GEMM: C = A(f32,[4096][1024]) x Bm(bf16,[1024][1024], row-major-K "B^T")
// MODE 0: bf16 out scattered to [n][t][d]   (K path)
// MODE 1: same + *0.125                      (Q path)
// MODE 2: f32 out [4096][1024] + bias        (output path)
// MODE 3: bf16 out scattered to [n][d][s]    (V path, transposed for PV B-frags)
template<int MODE>
__global__ __launch_bounds__(256) void gemm_bt(const float* __restrict__ A,
                                               const ushort* __restrict__ Bm,
                                               void* __restrict__ Cout,
                                               const float* __restrict__ bias){
  constexpr int BK = 32;
  __shared__ ushort lA[128 * BK];
  __shared__ ushort lB[128 * BK];
  const int tid = threadIdx.x;
  const int l = tid & 63, w = tid >> 6;
  const int wm = w >> 1, wn = w & 1;
  const int lq = l >> 4, lr = l & 15;
  const int m0 = blockIdx.y * 128, n0 = blockIdx.x * 128;
  const int srow = tid >> 1, shalf = tid & 1;

  f32x4 acc[4][4];
  #pragma unroll
  for (int i = 0; i < 4; i++)
    #pragma unroll
    for (int j = 0; j < 4; j++) acc[i][j] = (f32x4){0.f, 0.f, 0.f, 0.f};

  for (int k0 = 0; k0 < K_DIM; k0 += BK){
    {
      const float* ga = A + (size_t)(m0 + srow) * K_DIM + k0 + shalf * 16;
      ushort tmp[16];
      #pragma unroll
      for (int j = 0; j < 16; j += 4){
        float4 vv = *reinterpret_cast<const float4*>(ga + j);
        tmp[j] = f2bf(vv.x); tmp[j+1] = f2bf(vv.y); tmp[j+2] = f2bf(vv.z); tmp[j+3] = f2bf(vv.w);
      }
      #pragma unroll
      for (int j = 0; j < 2; j++){
        int slot = (shalf * 2 + j) ^ (srow & 3);
        *reinterpret_cast<short8*>(reinterpret_cast<char*>(lA) + srow * 64 + slot * 16) =
            *reinterpret_cast<short8*>(&tmp[j * 8]);
      }
      const ushort* gb = Bm + (size_t)(n0 + srow) * K_DIM + k0 + shalf * 16;
      #pragma unroll
      for (int j = 0; j < 2; j++){
        short8 vv = *reinterpret_cast<const short8*>(gb + j * 8);
        int slot = (shalf * 2 + j) ^ (srow & 3);
        *reinterpret_cast<short8*>(reinterpret_cast<char*>(lB) + srow * 64 + slot * 16) = vv;
      }
    }
    __syncthreads();
    short8 fa[4], fb[4];
    #pragma unroll
    for (int i = 0; i < 4; i++){
      int row = wm * 64 + i * 16 + lr;
      fa[i] = *reinterpret_cast<const short8*>(reinterpret_cast<const char*>(lA) + row * 64 + ((lq ^ (row & 3)) << 4));
      int col = wn * 64 + i * 16 + lr;
      fb[i] = *reinterpret_cast<const short8*>(reinterpret_cast<const char*>(lB) + col * 64 + ((lq ^ (col & 3)) << 4));
    }
    #pragma unroll
    for (int i = 0; i < 4; i++)
      #pragma unroll
      for (int j = 0; j < 4; j++)
        acc[i][j] = __builtin_amdgcn_mfma_f32_16x16x32_bf16(fa[i], fb[j], acc[i][j], 0, 0, 0);
    __syncthreads();
  }

  #pragma unroll
  for (int i = 0; i < 4; i++)
    #pragma unroll
    for (int j = 0; j < 4; j++)
      #pragma unroll
      for (int r = 0; r < 4; r++){
        int gm = m0 + wm * 64 + i * 16 + lq * 4 + r;
        int gn = n0 + wn * 64 + j * 16 + lr;
        float v = acc[i][j][r];
        if constexpr (MODE == 2){
          reinterpret_cast<float*>(Cout)[(size_t)gm * E_DIM + gn] = v + bias[gn];
        } else if constexpr (MODE == 3){
          int s = gm >> 3, b = gm & 7, h = gn >> 6, d = gn & 63;
          reinterpret_cast<ushort*>(Cout)[(((size_t)(b * H_CNT + h) * D_DIM + d) << 9) + s] = f2bf(v);
        } else {
          if constexpr (MODE == 1) v *= 0.125f;
          int t = gm >> 3, b = gm & 7, h = gn >> 6, d = gn & 63;
          reinterpret_cast<ushort*>(Cout)[(((size_t)(b * H_CNT + h) * T_DIM + t) << 6) + d] = f2bf(v);
        }
      }
}

// ---- fused monotonic-attention recurrence, one head per block ----
// LDS: p_sm[2][16][512] f32 (64KB) | a_buf[2][16][512] bf16 (32KB)  = 98304 B
// Roles per phase i: wave0 = recurrence chunk i; waves1-4 = PV chunk i-1
// (V-frags from global vpT, L2-resident); waves5-7 = energy/sigmoid chunk i+1.
__global__ __launch_bounds__(512) void rec_kernel(const ushort* __restrict__ qp,
                                                  const ushort* __restrict__ kp,
                                                  const ushort* __restrict__ vpT,
                                                  float* __restrict__ attn,
                                                  const float* __restrict__ ebias_p){
  extern __shared__ char smem[];
  const int tid = threadIdx.x;
  const int l = tid & 63, w = tid >> 6;
  const int kg = l >> 4, lr = l & 15;
  const int n = blockIdx.x;
  const int bb = n >> 4, hh = n & 15;
  const float ebias = ebias_p[0];

  const ushort* qph = qp + (size_t)n * (T_DIM * D_DIM);
  const ushort* kph = kp + (size_t)n * (S_DIM * D_DIM);

  float ap[8];
  #pragma unroll
  for (int j = 0; j < 8; j++) ap[j] = 0.f;
  if (l == 0) ap[0] = 1.f;

  auto energy = [&](int c, int ts, int stride){
    const int t0 = c << 4;
    char* pb = smem + ((c & 1) << 15);
    short8 fa0 = *reinterpret_cast<const short8*>(qph + (t0 + lr) * 64 + kg * 8);
    short8 fa1 = *reinterpret_cast<const short8*>(qph + (t0 + lr) * 64 + 32 + kg * 8);
    for (int tile = ts; tile < 32; tile += stride){
      int s0 = tile << 4;
      short8 fb0 = *reinterpret_cast<const short8*>(kph + (s0 + lr) * 64 + kg * 8);
      short8 fb1 = *reinterpret_cast<const short8*>(kph + (s0 + lr) * 64 + 32 + kg * 8);
      f32x4 e = (f32x4){0.f, 0.f, 0.f, 0.f};
      e = __builtin_amdgcn_mfma_f32_16x16x32_bf16(fa0, fb0, e, 0, 0, 0);
      e = __builtin_amdgcn_mfma_f32_16x16x32_bf16(fa1, fb1, e, 0, 0, 0);
      #pragma unroll
      for (int r = 0; r < 4; ++r){
        float pv = rcpf(1.f + __expf(-(e[r] + ebias)));
        *reinterpret_cast<float*>(pb + (((kg << 2) + r) << 11) + ((s0 + lr) << 2)) = pv;
      }
    }
  };

  // prologue: energy for chunk 0 across all 8 waves
  energy(0, w, 8);
  __syncthreads();

  for (int i = 0; i <= 32; ++i){
    if (w == 0){
      if (i < 32){
        // ---- 16 serial recurrence steps, single wave, DPP scans ----
        char* pb = smem + ((i & 1) << 15);
        char* ab = smem + 65536 + ((i & 1) << 14);
        f32x4 pA = *reinterpret_cast<const f32x4*>(pb + l * 32);
        f32x4 pB = *reinterpret_cast<const f32x4*>(pb + l * 32 + 16);
        #pragma unroll
        for (int tt = 0; tt < 16; ++tt){
          f32x4 nA, nB;
          if (tt < 15){
            nA = *reinterpret_cast<const f32x4*>(pb + ((tt + 1) << 11) + l * 32);
            nB = *reinterpret_cast<const f32x4*>(pb + ((tt + 1) << 11) + l * 32 + 16);
          }
          float pc[8] = {pA[0], pA[1], pA[2], pA[3], pB[0], pB[1], pB[2], pB[3]};
          // in-lane inclusive cumprod of (1-p)
          float cm[8];
          cm[0] = 1.f - pc[0];
          #pragma unroll
          for (int j = 1; j < 8; j++) cm[j] = cm[j-1] * (1.f - pc[j]);
          float Tm = wscan_mul(cm[7]);
          float Em = dppf<0x138,0xf>(Tm, 1.f);   // wave_shr:1 -> exclusive
          float cp[8];
          cp[0] = Em;
          #pragma unroll
          for (int j = 1; j < 8; j++) cp[j] = Em * cm[j-1];
          // cumsum of ap/clamp(cp)
          float ds[8];
          ds[0] = ap[0] * rcpf(fmaxf(cp[0], EPS_C));
          #pragma unroll
          for (int j = 1; j < 8; j++) ds[j] = ds[j-1] + ap[j] * rcpf(fmaxf(cp[j], EPS_C));
          float Ta = wscan_add(ds[7]);
          float Ea = dppf<0x138,0xf>(Ta, 0.f);
          float al[8];
          #pragma unroll
          for (int j = 0; j < 8; j++) al[j] = fminf(pc[j] * cp[j] * (Ea + ds[j]), 1.f);
          // row total (for mass-dump fix at s=511), off critical path
          float ls = ((al[0] + al[1]) + (al[2] + al[3])) + ((al[4] + al[5]) + (al[6] + al[7]));
          float St = wscan_add(ls);
          short8 ob;
          #pragma unroll
          for (int j = 0; j < 8; j++){ ob[j] = (short)f2bf(al[j]); ap[j] = al[j]; }
          if (l == 63){
            float fx = 1.f - fminf(fmaxf(St - al[7], 0.f), 1.f);
            ob[7] = (short)f2bf(fx);
          }
          *reinterpret_cast<short8*>(ab + (((tt << 10) + (l << 4)) ^ ((tt & 7) << 4))) = ob;
          if (tt < 15){ pA = nA; pB = nB; }
        }
      }
    } else if (w <= 4){
      if (i >= 1){
        // ---- PV for chunk i-1: C[16t x 16d] per wave, K=512 ----
        const int c1 = i - 1;
        const int dcol = ((w - 1) << 4) + lr;
        const ushort* vb = vpT + ((size_t)n * 64 + dcol) * 512;
        const char* ab = smem + 65536 + ((c1 & 1) << 14);
        f32x4 ac = (f32x4){0.f, 0.f, 0.f, 0.f};
        #pragma unroll
        for (int kk = 0; kk < 16; ++kk){
          int sb = kk * 32 + kg * 8;
          short8 faA = *reinterpret_cast<const short8*>(ab + (((lr << 10) + (sb << 1)) ^ ((lr & 7) << 4)));
          short8 fbV = *reinterpret_cast<const short8*>(vb + sb);
          ac = __builtin_amdgcn_mfma_f32_16x16x32_bf16(faA, fbV, ac, 0, 0, 0);
        }
        const int t0 = c1 << 4;
        #pragma unroll
        for (int r = 0; r < 4; ++r){
          int tg = t0 + (kg << 2) + r;
          attn[((size_t)tg * B_DIM + bb) * E_DIM + hh * 64 + dcol] = ac[r];
        }
      }
    } else {
      if (i < 31) energy(i + 1, w - 5, 3);
    }
    __syncthreads();
  }
}

extern "C" void kernel_launch(void* const* d_in, const int* in_sizes, int n_in,
                              void* d_out, int out_size, void* d_ws, size_t ws_size,
                              hipStream_t stream){
  (void)in_sizes; (void)n_in; (void)out_size; (void)ws_size;
  const float* q  = (const float*)d_in[0];
  const float* k  = (const float*)d_in[1];
  const float* v  = (const float*)d_in[2];
  const float* Wq = (const float*)d_in[3];
  const float* Wk = (const float*)d_in[4];
  const float* Wv = (const float*)d_in[5];
  const float* Wo = (const float*)d_in[6];
  const float* bo = (const float*)d_in[7];
  const float* eb = (const float*)d_in[8];

  char* ws = (char*)d_ws;
  ushort* wqt  = (ushort*)(ws);
  ushort* wkt  = (ushort*)(ws + (1u << 21));
  ushort* wvt  = (ushort*)(ws + 2u * (1u << 21));
  ushort* wot  = (ushort*)(ws + 3u * (1u << 21));
  ushort* qp   = (ushort*)(ws + 4u * (1u << 21));
  ushort* kp   = (ushort*)(ws + 4u * (1u << 21) + (1u << 23));
  ushort* vpT  = (ushort*)(ws + 4u * (1u << 21) + 2u * (1u << 23));
  float*  attn = (float*) (ws + 4u * (1u << 21) + 3u * (1u << 23));

  dim3 tb(256);
  dim3 tgT(32, 32);
  wtrans_kernel<<<tgT, tb, 0, stream>>>(Wq, wqt);
  wtrans_kernel<<<tgT, tb, 0, stream>>>(Wk, wkt);
  wtrans_kernel<<<tgT, tb, 0, stream>>>(Wv, wvt);
  wtrans_kernel<<<tgT, tb, 0, stream>>>(Wo, wot);

  dim3 gg(E_DIM / 128, M_ROWS / 128);
  gemm_bt<1><<<gg, tb, 0, stream>>>(q, wqt, (void*)qp, nullptr);
  gemm_bt<0><<<gg, tb, 0, stream>>>(k, wkt, (void*)kp, nullptr);
  gemm_bt<3><<<gg, tb, 0, stream>>>(v, wvt, (void*)vpT, nullptr);

  hipFuncSetAttribute((const void*)rec_kernel,
                      hipFuncAttributeMaxDynamicSharedMemorySize, 98304);
  rec_kernel<<<dim3(N_HEADS), dim3(512), 98304, stream>>>(qp, kp, vpT, attn, eb);

  gemm_bt<2><<<gg, tb, 0, stream>>>(attn, wot, d_out, bo);
}

// Round 3
// 403.825 us; speedup vs baseline: 2.3955x; 1.2087x over previous
//
#include <hip/hip_runtime.h>
#include <hip/hip_bf16.h>

#define T_DIM 512
#define S_DIM 512
#define B_DIM 8
#define E_DIM 1024
#define H_CNT 16
#define D_DIM 64
#define N_HEADS 128
#define M_ROWS 4096
#define K_DIM 1024
#define EPS_C 1e-6f

// rec_kernel LDS map (163840 B total):
#define LDS_A   0        // alpha bf16: 2 x 16 x 512 x 2 = 32768
#define LDS_P   32768    // (1-p) u16 : 2 x 16 x 512 x 2 = 32768
#define LDS_X   65536    // cpr  f32  : 2 x 16 x 512 x 4 = 65536
#define LDS_PCP 131072   // p*cp bf16 : 2 x 16 x 512 x 2 = 32768

using f32x4  = __attribute__((ext_vector_type(4))) float;
using short8 = __attribute__((ext_vector_type(8))) short;

static __device__ __forceinline__ ushort f2bf(float x){
  __hip_bfloat16 h = __float2bfloat16(x);
  return *reinterpret_cast<ushort*>(&h);
}
static __device__ __forceinline__ float bf2f_u(int u){
  return __int_as_float((u & 0xFFFF) << 16);
}
static __device__ __forceinline__ float rcpf(float x){
  return __builtin_amdgcn_rcpf(x);
}

template<int CTRL, int RMASK>
static __device__ __forceinline__ float dppf(float x, float oldv){
  return __int_as_float(__builtin_amdgcn_update_dpp(
      __float_as_int(oldv), __float_as_int(x), CTRL, RMASK, 0xf, false));
}
static __device__ __forceinline__ float wscan_mul(float x){
  x *= dppf<0x111,0xf>(x, 1.f);
  x *= dppf<0x112,0xf>(x, 1.f);
  x *= dppf<0x114,0xf>(x, 1.f);
  x *= dppf<0x118,0xf>(x, 1.f);
  x *= dppf<0x142,0xa>(x, 1.f);
  x *= dppf<0x143,0xc>(x, 1.f);
  return x;
}
static __device__ __forceinline__ float wscan_add(float x){
  x += dppf<0x111,0xf>(x, 0.f);
  x += dppf<0x112,0xf>(x, 0.f);
  x += dppf<0x114,0xf>(x, 0.f);
  x += dppf<0x118,0xf>(x, 0.f);
  x += dppf<0x142,0xa>(x, 0.f);
  x += dppf<0x143,0xc>(x, 0.f);
  return x;
}

// ---- batched transpose + cvt: Wt[f][e] = bf16(W[e][f]), 4 mats via z ----
__global__ __launch_bounds__(256) void wtrans4(const float* __restrict__ W0,
                                               const float* __restrict__ W1,
                                               const float* __restrict__ W2,
                                               const float* __restrict__ W3,
                                               ushort* __restrict__ T0,
                                               ushort* __restrict__ T1,
                                               ushort* __restrict__ T2,
                                               ushort* __restrict__ T3){
  const int z = blockIdx.z;
  const float* W = (z == 0) ? W0 : (z == 1) ? W1 : (z == 2) ? W2 : W3;
  ushort* Wt     = (z == 0) ? T0 : (z == 1) ? T1 : (z == 2) ? T2 : T3;
  __shared__ float tile[32][33];
  const int bx = blockIdx.x * 32, by = blockIdx.y * 32;
  const int x = threadIdx.x & 31, y = threadIdx.x >> 5;
  #pragma unroll
  for (int j = 0; j < 32; j += 8)
    tile[y + j][x] = W[(size_t)(by + y + j) * E_DIM + bx + x];
  __syncthreads();
  #pragma unroll
  for (int j = 0; j < 32; j += 8)
    Wt[(size_t)(bx + y + j) * E_DIM + by + x] = f2bf(tile[x][y + j]);
}

// ---- GEMM core: C = A x Bm(bf16 [N][K] row-major-K) ----
// MODE 0: bf16 out -> [n][t][d]; MODE 1: same * 0.125; MODE 2: f32 out + bias;
// MODE 3: bf16 out -> [n][d][s].  ABF: A is bf16 (else f32).
template<int MODE, bool ABF>
static __device__ __forceinline__ void gemm_core(const void* __restrict__ Ap,
                                                 const ushort* __restrict__ Bm,
                                                 void* __restrict__ Cout,
                                                 const float* __restrict__ bias,
                                                 int bx, int by){
  constexpr int BK = 32;
  __shared__ ushort lA[128 * BK];
  __shared__ ushort lB[128 * BK];
  const int tid = threadIdx.x;
  const int l = tid & 63, w = tid >> 6;
  const int wm = w >> 1, wn = w & 1;
  const int lq = l >> 4, lr = l & 15;
  const int m0 = by * 128, n0 = bx * 128;
  const int srow = tid >> 1, shalf = tid & 1;

  f32x4 acc[4][4];
  #pragma unroll
  for (int i = 0; i < 4; i++)
    #pragma unroll
    for (int j = 0; j < 4; j++) acc[i][j] = (f32x4){0.f, 0.f, 0.f, 0.f};

  for (int k0 = 0; k0 < K_DIM; k0 += BK){
    if constexpr (ABF){
      const ushort* ga = (const ushort*)Ap + (size_t)(m0 + srow) * K_DIM + k0 + shalf * 16;
      #pragma unroll
      for (int j = 0; j < 2; j++){
        short8 vv = *reinterpret_cast<const short8*>(ga + j * 8);
        int slot = (shalf * 2 + j) ^ (srow & 3);
        *reinterpret_cast<short8*>(reinterpret_cast<char*>(lA) + srow * 64 + slot * 16) = vv;
      }
    } else {
      const float* ga = (const float*)Ap + (size_t)(m0 + srow) * K_DIM + k0 + shalf * 16;
      ushort tmp[16];
      #pragma unroll
      for (int j = 0; j < 16; j += 4){
        float4 vv = *reinterpret_cast<const float4*>(ga + j);
        tmp[j] = f2bf(vv.x); tmp[j+1] = f2bf(vv.y); tmp[j+2] = f2bf(vv.z); tmp[j+3] = f2bf(vv.w);
      }
      #pragma unroll
      for (int j = 0; j < 2; j++){
        int slot = (shalf * 2 + j) ^ (srow & 3);
        *reinterpret_cast<short8*>(reinterpret_cast<char*>(lA) + srow * 64 + slot * 16) =
            *reinterpret_cast<short8*>(&tmp[j * 8]);
      }
    }
    {
      const ushort* gb = Bm + (size_t)(n0 + srow) * K_DIM + k0 + shalf * 16;
      #pragma unroll
      for (int j = 0; j < 2; j++){
        short8 vv = *reinterpret_cast<const short8*>(gb + j * 8);
        int slot = (shalf * 2 + j) ^ (srow & 3);
        *reinterpret_cast<short8*>(reinterpret_cast<char*>(lB) + srow * 64 + slot * 16) = vv;
      }
    }
    __syncthreads();
    short8 fa[4], fb[4];
    #pragma unroll
    for (int i = 0; i < 4; i++){
      int row = wm * 64 + i * 16 + lr;
      fa[i] = *reinterpret_cast<const short8*>(reinterpret_cast<const char*>(lA) + row * 64 + ((lq ^ (row & 3)) << 4));
      int col = wn * 64 + i * 16 + lr;
      fb[i] = *reinterpret_cast<const short8*>(reinterpret_cast<const char*>(lB) + col * 64 + ((lq ^ (col & 3)) << 4));
    }
    #pragma unroll
    for (int i = 0; i < 4; i++)
      #pragma unroll
      for (int j = 0; j < 4; j++)
        acc[i][j] = __builtin_amdgcn_mfma_f32_16x16x32_bf16(fa[i], fb[j], acc[i][j], 0, 0, 0);
    __syncthreads();
  }

  #pragma unroll
  for (int i = 0; i < 4; i++)
    #pragma unroll
    for (int j = 0; j < 4; j++)
      #pragma unroll
      for (int r = 0; r < 4; r++){
        int gm = m0 + wm * 64 + i * 16 + lq * 4 + r;
        int gn = n0 + wn * 64 + j * 16 + lr;
        float v = acc[i][j][r];
        if constexpr (MODE == 2){
          reinterpret_cast<float*>(Cout)[(size_t)gm * E_DIM + gn] = v + bias[gn];
        } else if constexpr (MODE == 3){
          int s = gm >> 3, b = gm & 7, h = gn >> 6, d = gn & 63;
          reinterpret_cast<ushort*>(Cout)[(((size_t)(b * H_CNT + h) * D_DIM + d) << 9) + s] = f2bf(v);
        } else {
          if constexpr (MODE == 1) v *= 0.125f;
          int t = gm >> 3, b = gm & 7, h = gn >> 6, d = gn & 63;
          reinterpret_cast<ushort*>(Cout)[(((size_t)(b * H_CNT + h) * T_DIM + t) << 6) + d] = f2bf(v);
        }
      }
}

__global__ __launch_bounds__(256) void gemm_qkv(const float* __restrict__ q,
                                                const float* __restrict__ k,
                                                const float* __restrict__ v,
                                                const ushort* __restrict__ wqt,
                                                const ushort* __restrict__ wkt,
                                                const ushort* __restrict__ wvt,
                                                ushort* __restrict__ qp,
                                                ushort* __restrict__ kp,
                                                ushort* __restrict__ vpT){
  if (blockIdx.z == 0)      gemm_core<1,false>(q, wqt, qp,  nullptr, blockIdx.x, blockIdx.y);
  else if (blockIdx.z == 1) gemm_core<0,false>(k, wkt, kp,  nullptr, blockIdx.x, blockIdx.y);
  else                      gemm_core<3,false>(v, wvt, vpT, nullptr, blockIdx.x, blockIdx.y);
}

__global__ __launch_bounds__(256) void gemm_out(const ushort* __restrict__ attn_bf,
                                                const ushort* __restrict__ wot,
                                                float* __restrict__ out,
                                                const float* __restrict__ bo){
  gemm_core<2,true>(attn_bf, wot, out, bo, blockIdx.x, blockIdx.y);
}

// ---- fused monotonic-attention recurrence, 4-stage pipeline ----
// phase ph: E(ph) on waves5-7 (energy -> 1-p u16), X(ph-1) on waves5-7
// (cumprod scan -> cpr f32 + pcp bf16), R(ph-2) on wave0 (ap-chain only),
// P(ph-3) on waves1-4 (alpha x V -> attn bf16). One barrier per phase.
__global__ __launch_bounds__(512) void rec_kernel(const ushort* __restrict__ qp,
                                                  const ushort* __restrict__ kp,
                                                  const ushort* __restrict__ vpT,
                                                  ushort* __restrict__ attn_bf,
                                                  const float* __restrict__ ebias_p){
  extern __shared__ char smem[];
  const int tid = threadIdx.x;
  const int l = tid & 63, w = tid >> 6;
  const int kg = l >> 4, lr = l & 15;
  const int n = blockIdx.x;
  const int bb = n >> 4, hh = n & 15;
  const float ebias = ebias_p[0];

  const ushort* qph = qp + (size_t)n * (T_DIM * D_DIM);
  const ushort* kph = kp + (size_t)n * (S_DIM * D_DIM);

  float ap[8];
  #pragma unroll
  for (int j = 0; j < 8; j++) ap[j] = 0.f;
  if (l == 0) ap[0] = 1.f;

  for (int ph = 0; ph <= 34; ++ph){
    if (w == 0){
      // ---------------- R(c): recurrence, minimal ap-chain ----------------
      const int c = ph - 2;
      if (c >= 0 && c < 32){
        const char* xb = smem + LDS_X   + ((c & 1) << 15);
        const char* cb = smem + LDS_PCP + ((c & 1) << 14);
        char*       ab = smem + LDS_A   + ((c & 1) << 14);
        f32x4 c0 = *reinterpret_cast<const f32x4*>(xb + (l << 5));
        f32x4 c1 = *reinterpret_cast<const f32x4*>(xb + (l << 5) + 16);
        short8 pv = *reinterpret_cast<const short8*>(cb + (l << 4));
        #pragma unroll
        for (int tt = 0; tt < 16; ++tt){
          f32x4 n0v, n1v; short8 npv;
          if (tt < 15){
            n0v = *reinterpret_cast<const f32x4*>(xb + ((tt + 1) << 11) + (l << 5));
            n1v = *reinterpret_cast<const f32x4*>(xb + ((tt + 1) << 11) + (l << 5) + 16);
            npv = *reinterpret_cast<const short8*>(cb + ((tt + 1) << 10) + (l << 4));
          }
          float z0 = ap[0]*c0[0], z1 = ap[1]*c0[1], z2 = ap[2]*c0[2], z3 = ap[3]*c0[3];
          float z4 = ap[4]*c1[0], z5 = ap[5]*c1[1], z6 = ap[6]*c1[2], z7 = ap[7]*c1[3];
          // depth-3 inclusive prefix (Ladner-Fischer)
          float a1 = z0+z1, a3 = z2+z3, a5 = z4+z5, a7 = z6+z7;
          float b3 = a1+a3, b7 = a5+a7, e6 = a5+z6;
          float d0 = z0, d1 = a1, d2 = a1+z2, d3 = b3;
          float d4 = b3+z4, d5 = b3+a5, d6 = b3+e6, d7 = b3+b7;
          float Ta = wscan_add(d7);
          float Ea = dppf<0x138,0xf>(Ta, 0.f);
          float al[8];
          al[0] = fminf(bf2f_u(pv[0]) * (Ea + d0), 1.f);
          al[1] = fminf(bf2f_u(pv[1]) * (Ea + d1), 1.f);
          al[2] = fminf(bf2f_u(pv[2]) * (Ea + d2), 1.f);
          al[3] = fminf(bf2f_u(pv[3]) * (Ea + d3), 1.f);
          al[4] = fminf(bf2f_u(pv[4]) * (Ea + d4), 1.f);
          al[5] = fminf(bf2f_u(pv[5]) * (Ea + d5), 1.f);
          al[6] = fminf(bf2f_u(pv[6]) * (Ea + d6), 1.f);
          al[7] = fminf(bf2f_u(pv[7]) * (Ea + d7), 1.f);
          // row-total for mass-dump fixup (off critical path)
          float ls = ((al[0]+al[1])+(al[2]+al[3])) + ((al[4]+al[5])+(al[6]+al[7]));
          float St = wscan_add(ls);
          short8 ob;
          #pragma unroll
          for (int j = 0; j < 8; j++){ ob[j] = (short)f2bf(al[j]); ap[j] = al[j]; }
          if (l == 63){
            float fx = 1.f - fminf(fmaxf(St - al[7], 0.f), 1.f);
            ob[7] = (short)f2bf(fx);
          }
          *reinterpret_cast<short8*>(ab + ((((tt) << 10) + (l << 4)) ^ ((tt & 7) << 4))) = ob;
          if (tt < 15){ c0 = n0v; c1 = n1v; pv = npv; }
        }
      }
    } else if (w <= 4){
      // ---------------- P(c): alpha x V -> attn (bf16) ----------------
      const int c = ph - 3;
      if (c >= 0){
        const int dcol = ((w - 1) << 4) + lr;
        const ushort* vb = vpT + ((size_t)n * 64 + dcol) * 512;
        const char* ab = smem + LDS_A + ((c & 1) << 14);
        f32x4 ac = (f32x4){0.f, 0.f, 0.f, 0.f};
        #pragma unroll
        for (int kk = 0; kk < 16; ++kk){
          int sb = kk * 32 + kg * 8;
          short8 faA = *reinterpret_cast<const short8*>(ab + (((lr << 10) + (sb << 1)) ^ ((lr & 7) << 4)));
          short8 fbV = *reinterpret_cast<const short8*>(vb + sb);
          ac = __builtin_amdgcn_mfma_f32_16x16x32_bf16(faA, fbV, ac, 0, 0, 0);
        }
        const int t0 = c << 4;
        #pragma unroll
        for (int r = 0; r < 4; ++r){
          int tg = t0 + (kg << 2) + r;
          attn_bf[((size_t)tg * B_DIM + bb) * E_DIM + hh * 64 + dcol] = f2bf(ac[r]);
        }
      }
    } else {
      // ---------------- X(c-): p -> cpr,pcp ----------------
      const int cx = ph - 1;
      if (cx >= 0 && cx < 32){
        const char* pb = smem + LDS_P   + ((cx & 1) << 14);
        char*       xb = smem + LDS_X   + ((cx & 1) << 15);
        char*       cb = smem + LDS_PCP + ((cx & 1) << 14);
        for (int tt = w - 5; tt < 16; tt += 3){
          short8 uv = *reinterpret_cast<const short8*>(pb + (tt << 10) + (l << 4));
          float om[8], p[8];
          #pragma unroll
          for (int j = 0; j < 8; j++){
            om[j] = (float)(((int)uv[j]) & 0xFFFF) * (1.f / 65535.f);
            p[j] = 1.f - om[j];
          }
          // depth-3 inclusive cumprod
          float a1 = om[0]*om[1], a3 = om[2]*om[3], a5 = om[4]*om[5], a7 = om[6]*om[7];
          float b3 = a1*a3, b7 = a5*a7, e6 = a5*om[6];
          float m[8];
          m[0] = om[0]; m[1] = a1; m[2] = a1*om[2]; m[3] = b3;
          m[4] = b3*om[4]; m[5] = b3*a5; m[6] = b3*e6; m[7] = b3*b7;
          float Tm = wscan_mul(m[7]);
          float Em = dppf<0x138,0xf>(Tm, 1.f);
          float cp[8];
          cp[0] = Em;
          #pragma unroll
          for (int j = 1; j < 8; j++) cp[j] = Em * m[j-1];
          float cr[8], pc[8];
          #pragma unroll
          for (int j = 0; j < 8; j++){
            cr[j] = rcpf(fmaxf(cp[j], EPS_C));
            pc[j] = p[j] * cp[j];
          }
          f32x4 w0 = (f32x4){cr[0], cr[1], cr[2], cr[3]};
          f32x4 w1 = (f32x4){cr[4], cr[5], cr[6], cr[7]};
          *reinterpret_cast<f32x4*>(xb + (tt << 11) + (l << 5)) = w0;
          *reinterpret_cast<f32x4*>(xb + (tt << 11) + (l << 5) + 16) = w1;
          short8 pcb;
          #pragma unroll
          for (int j = 0; j < 8; j++) pcb[j] = (short)f2bf(pc[j]);
          *reinterpret_cast<short8*>(cb + (tt << 10) + (l << 4)) = pcb;
        }
      }
      // ---------------- E(c): energy -> (1-p) u16 ----------------
      const int ce = ph;
      if (ce < 32){
        const int t0 = ce << 4;
        char* pb = smem + LDS_P + ((ce & 1) << 14);
        short8 fa0 = *reinterpret_cast<const short8*>(qph + (t0 + lr) * 64 + kg * 8);
        short8 fa1 = *reinterpret_cast<const short8*>(qph + (t0 + lr) * 64 + 32 + kg * 8);
        for (int tile = w - 5; tile < 32; tile += 3){
          int s0 = tile << 4;
          short8 fb0 = *reinterpret_cast<const short8*>(kph + (s0 + lr) * 64 + kg * 8);
          short8 fb1 = *reinterpret_cast<const short8*>(kph + (s0 + lr) * 64 + 32 + kg * 8);
          f32x4 e = (f32x4){0.f, 0.f, 0.f, 0.f};
          e = __builtin_amdgcn_mfma_f32_16x16x32_bf16(fa0, fb0, e, 0, 0, 0);
          e = __builtin_amdgcn_mfma_f32_16x16x32_bf16(fa1, fb1, e, 0, 0, 0);
          #pragma unroll
          for (int r = 0; r < 4; ++r){
            float om = rcpf(1.f + __expf(e[r] + ebias));   // = 1 - sigmoid
            uint u = (uint)(om * 65535.f + 0.5f);
            *reinterpret_cast<ushort*>(pb + (((kg << 2) + r) << 10) + ((s0 + lr) << 1)) = (ushort)u;
          }
        }
      }
    }
    __syncthreads();
  }
}

extern "C" void kernel_launch(void* const* d_in, const int* in_sizes, int n_in,
                              void* d_out, int out_size, void* d_ws, size_t ws_size,
                              hipStream_t stream){
  (void)in_sizes; (void)n_in; (void)out_size; (void)ws_size;
  const float* q  = (const float*)d_in[0];
  const float* k  = (const float*)d_in[1];
  const float* v  = (const float*)d_in[2];
  const float* Wq = (const float*)d_in[3];
  const float* Wk = (const float*)d_in[4];
  const float* Wv = (const float*)d_in[5];
  const float* Wo = (const float*)d_in[6];
  const float* bo = (const float*)d_in[7];
  const float* eb = (const float*)d_in[8];

  char* ws = (char*)d_ws;
  ushort* wqt  = (ushort*)(ws);
  ushort* wkt  = (ushort*)(ws + (1u << 21));
  ushort* wvt  = (ushort*)(ws + 2u * (1u << 21));
  ushort* wot  = (ushort*)(ws + 3u * (1u << 21));
  ushort* qp   = (ushort*)(ws + 4u * (1u << 21));
  ushort* kp   = (ushort*)(ws + 4u * (1u << 21) + (1u << 23));
  ushort* vpT  = (ushort*)(ws + 4u * (1u << 21) + 2u * (1u << 23));
  ushort* attn = (ushort*)(ws + 4u * (1u << 21) + 3u * (1u << 23));

  wtrans4<<<dim3(32, 32, 4), dim3(256), 0, stream>>>(Wq, Wk, Wv, Wo, wqt, wkt, wvt, wot);

  gemm_qkv<<<dim3(E_DIM / 128, M_ROWS / 128, 3), dim3(256), 0, stream>>>(
      q, k, v, wqt, wkt, wvt, qp, kp, vpT);

  hipFuncSetAttribute((const void*)rec_kernel,
                      hipFuncAttributeMaxDynamicSharedMemorySize, 163840);
  rec_kernel<<<dim3(N_HEADS), dim3(512), 163840, stream>>>(qp, kp, vpT, attn, eb);

  gemm_out<<<dim3(E_DIM / 128, M_ROWS / 128), dim3(256), 0, stream>>>(attn, wot, (float*)d_out, bo);
}